// Round 4
// baseline (126.981 us; speedup 1.0000x reference)
//
#include <hip/hip_runtime.h>
#include <math.h>

#define B 8
#define T 128
#define NKEY 127   // t-1
#define NPAD 128   // padded key count (score row 127 forced to prob 0)
#define KDIM 64    // Q_DIM == KV_DIM
#define NH 4       // heads
#define CH 256     // NH*KDIM output channels

typedef short short8 __attribute__((ext_vector_type(8)));   // 8 bf16 (4 VGPRs)
typedef float floatx4 __attribute__((ext_vector_type(4)));  // MFMA C/D

// tanh(x) = 1 - 2/(e^{2x}+1). Saturates correctly at +/-inf, no clamp needed.
__device__ __forceinline__ float fast_tanh(float x) {
    float e = __expf(2.f * x);
    float r = __builtin_amdgcn_rcpf(e + 1.f);
    return fmaf(-2.f, r, 1.f);
}

// Truncation split: x = hi + lo (+ ~2^-24 rel error), both bf16.
__device__ __forceinline__ void split8(const float4& a, const float4& b,
                                       short8& hi, short8& lo) {
    float x[8] = {a.x, a.y, a.z, a.w, b.x, b.y, b.z, b.w};
    #pragma unroll
    for (int i = 0; i < 8; ++i) {
        unsigned u = __float_as_uint(x[i]);
        hi[i] = (short)(u >> 16);                          // trunc to bf16
        float l = x[i] - __uint_as_float(u & 0xFFFF0000u); // exact residual
        lo[i] = (short)(__float_as_uint(l) >> 16);         // trunc residual
    }
}

// One workgroup per (b,t): 4 waves; wave h == head h.
// R4: no fp32 kv staging in LDS (was 32.5 KB -> 2 blocks/CU). Conversion and
// Phase B read kv through L1/L2 instead; LDS ~36 KB -> 4 blocks/CU.
// Fragment writes remapped lane-linear -> zero bank conflicts.
__global__ __launch_bounds__(256, 4)
void attn_kernel(const float* __restrict__ q_x,   // (B,T,64)
                 const float* __restrict__ kv_x,  // (B,T,127,64)
                 const float* __restrict__ Wk,    // (256,64)
                 const float* __restrict__ Wq,    // (256,64)
                 const float* __restrict__ Wv,    // (256,64)
                 const float* __restrict__ bias,  // (64,)
                 const float* __restrict__ Ws,    // (1,64)
                 const float* __restrict__ bs,    // (1,) -- cancels in softmax
                 float* __restrict__ out)         // (B,T,256)
{
    __shared__ __align__(16) short bh_lds[16][64][8];    // 16 KB: B-frag hi [chunk][lane][8]
    __shared__ __align__(16) short bl_lds[16][64][8];    // 16 KB: B-frag lo
    __shared__ float qb_lds[CH];                         // 1 KB: query+bias per channel
    __shared__ float p_lds[NH][NPAD];                    // 2 KB: scores then probs
    __shared__ float wkv_lds[NH][KDIM];                  // 1 KB

    const int bt   = blockIdx.x;
    const int tid  = threadIdx.x;
    const int h    = tid >> 6;    // wave == head
    const int lane = tid & 63;
    const int col  = lane & 15;   // MFMA n/m lane index
    const int quad = lane >> 4;   // MFMA k-group / row-group

    const float* __restrict__ kvg = kv_x + (size_t)bt * NKEY * KDIM;

    // ---- convert kv (global, L1/L2) -> fragment-ordered bf16 hi/lo LDS ----
    // chunk = nt*2+ks; fragment lane fl == lane -> write addr chunk*1024+lane*16
    // (lane-linear per wave: conflict-free b128 writes).
    // Fragment content: kv[nt*16 + (lane&15)][ks*32 + (lane>>4)*8 + j]
    #pragma unroll
    for (int w = 0; w < 4; ++w) {
        const int chunk = w * 4 + h;          // each wave does 4 chunks
        const int nt = chunk >> 1, ks = chunk & 1;
        const int n  = nt * 16 + (lane & 15);
        const int k0 = ks * 32 + (lane >> 4) * 8;
        float4 a = make_float4(0.f, 0.f, 0.f, 0.f);
        float4 b = make_float4(0.f, 0.f, 0.f, 0.f);
        if (n < NKEY) {
            const float* p = kvg + (size_t)n * KDIM + k0;
            a = *(const float4*)p;
            b = *(const float4*)(p + 4);
        }
        short8 hi, lo;
        split8(a, b, hi, lo);
        *(short8*)&bh_lds[chunk][lane][0] = hi;
        *(short8*)&bl_lds[chunk][lane][0] = lo;
    }

    // ---- query_j + bias -> qb_lds[channel] (q row broadcast via cache) ----
    {
        const float4* Wq4 = (const float4*)(Wq + (size_t)tid * KDIM);
        const float4* q4g = (const float4*)(q_x + (size_t)bt * KDIM);
        float4 qa = {0.f, 0.f, 0.f, 0.f};
        #pragma unroll
        for (int i = 0; i < 16; ++i) {
            float4 w = Wq4[i];
            float4 q4 = q4g[i];
            qa.x = fmaf(q4.x, w.x, qa.x);
            qa.y = fmaf(q4.y, w.y, qa.y);
            qa.z = fmaf(q4.z, w.z, qa.z);
            qa.w = fmaf(q4.w, w.w, qa.w);
        }
        qb_lds[tid] = (qa.x + qa.y) + (qa.z + qa.w) + bias[tid & 63];
    }

    // ---- A-fragments (Wk rows of this head) from global, split hi/lo ----
    // A layout: lane holds Wk[h*64 + jt*16 + col][ks*32 + quad*8 + j]
    short8 ahi[4][2], alo[4][2];
    #pragma unroll
    for (int jt = 0; jt < 4; ++jt)
        #pragma unroll
        for (int ks = 0; ks < 2; ++ks) {
            const float* wrow = Wk + (size_t)(h * 64 + jt * 16 + col) * KDIM
                                   + ks * 32 + quad * 8;
            float4 a = *(const float4*)wrow;
            float4 b = *(const float4*)(wrow + 4);
            split8(a, b, ahi[jt][ks], alo[jt][ks]);
        }

    __syncthreads();   // frags + qb ready

    // ---- per-lane qb / ws for epilogue: j = jt*16 + quad*4 + r ----
    float qbv[4][4], wsv[4][4];
    #pragma unroll
    for (int jt = 0; jt < 4; ++jt)
        #pragma unroll
        for (int r = 0; r < 4; ++r) {
            int j = jt * 16 + quad * 4 + r;
            qbv[jt][r] = qb_lds[h * 64 + j];
            wsv[jt][r] = Ws[j];
        }

    // ---- main loop: 8 n-tiles of 16 keys; 3-pass split-bf16 MFMA ----
    for (int nt = 0; nt < 8; ++nt) {
        short8 bhi0 = *(const short8*)&bh_lds[nt * 2 + 0][lane][0];
        short8 blo0 = *(const short8*)&bl_lds[nt * 2 + 0][lane][0];
        short8 bhi1 = *(const short8*)&bh_lds[nt * 2 + 1][lane][0];
        short8 blo1 = *(const short8*)&bl_lds[nt * 2 + 1][lane][0];

        floatx4 acc[4];
        #pragma unroll
        for (int jt = 0; jt < 4; ++jt) {
            floatx4 c = {0.f, 0.f, 0.f, 0.f};
            c = __builtin_amdgcn_mfma_f32_16x16x32_bf16(ahi[jt][0], bhi0, c, 0, 0, 0);
            c = __builtin_amdgcn_mfma_f32_16x16x32_bf16(ahi[jt][1], bhi1, c, 0, 0, 0);
            c = __builtin_amdgcn_mfma_f32_16x16x32_bf16(ahi[jt][0], blo0, c, 0, 0, 0);
            c = __builtin_amdgcn_mfma_f32_16x16x32_bf16(ahi[jt][1], blo1, c, 0, 0, 0);
            c = __builtin_amdgcn_mfma_f32_16x16x32_bf16(alo[jt][0], bhi0, c, 0, 0, 0);
            c = __builtin_amdgcn_mfma_f32_16x16x32_bf16(alo[jt][1], bhi1, c, 0, 0, 0);
            acc[jt] = c;
        }

        // epilogue: score[n] = sum_j tanh(key + qb[j]) * ws[j]
        // D layout: col = lane&15 = n in tile, row = quad*4 + r = j in jt
        float partial = 0.f;
        #pragma unroll
        for (int jt = 0; jt < 4; ++jt)
            #pragma unroll
            for (int r = 0; r < 4; ++r)
                partial = fmaf(fast_tanh(acc[jt][r] + qbv[jt][r]), wsv[jt][r], partial);
        partial += __shfl_xor(partial, 16, 64);   // reduce across quads (same col)
        partial += __shfl_xor(partial, 32, 64);
        if (lane < 16) p_lds[h][nt * 16 + lane] = partial;
    }
    // no barrier: wave h is sole writer+reader of p_lds[h][*]

    // ---- softmax over the 127 real keys (2 scores per lane) ----
    float invl;
    {
        float s_a = p_lds[h][lane];
        float s_b = p_lds[h][64 + lane];
        if (lane == 63) s_b = -1e30f;          // mask pad row 127
        float mx = fmaxf(s_a, s_b);
        #pragma unroll
        for (int off = 32; off > 0; off >>= 1)
            mx = fmaxf(mx, __shfl_xor(mx, off, 64));
        float pa = __expf(s_a - mx);
        float pb = __expf(s_b - mx);           // lane 63 -> 0
        float ls = pa + pb;
        #pragma unroll
        for (int off = 32; off > 0; off >>= 1)
            ls += __shfl_xor(ls, off, 64);
        invl = 1.f / ls;
        p_lds[h][lane]      = pa;
        p_lds[h][64 + lane] = pb;              // p_lds[h][127] = 0 masks pad
    }

    // ---- Phase B: wkv[h][lane] = (sum_n p[n] * kv[n][lane]) / l ----
    // kv column reads from global: consecutive lanes -> consecutive addrs,
    // L2-hot (just read in conversion).
    {
        float w0 = 0.f, w1 = 0.f, w2 = 0.f, w3 = 0.f;
        #pragma unroll 8
        for (int n4 = 0; n4 < NPAD; n4 += 4) {
            float4 p4 = *(const float4*)&p_lds[h][n4];   // uniform broadcast
            const int n3 = (n4 + 3 < NKEY) ? (n4 + 3) : 0;   // p4.w==0 there
            w0 = fmaf(p4.x, kvg[(size_t)(n4 + 0) * KDIM + lane], w0);
            w1 = fmaf(p4.y, kvg[(size_t)(n4 + 1) * KDIM + lane], w1);
            w2 = fmaf(p4.z, kvg[(size_t)(n4 + 2) * KDIM + lane], w2);
            w3 = fmaf(p4.w, kvg[(size_t)n3 * KDIM + lane], w3);
        }
        wkv_lds[h][lane] = ((w0 + w1) + (w2 + w3)) * invl;
    }
    // no barrier: wave-private

    // ---- Phase C: out[j] = wkv[h,:] . Wv[j,:] ----
    {
        const float4* Wv4 = (const float4*)(Wv + (size_t)tid * KDIM);
        const float4* wv_row = (const float4*)wkv_lds[h];
        float4 oa = {0.f, 0.f, 0.f, 0.f};
        #pragma unroll
        for (int i = 0; i < 16; ++i) {
            float4 w = Wv4[i];
            float4 c = wv_row[i];                        // broadcast
            oa.x = fmaf(c.x, w.x, oa.x);
            oa.y = fmaf(c.y, w.y, oa.y);
            oa.z = fmaf(c.z, w.z, oa.z);
            oa.w = fmaf(c.w, w.w, oa.w);
        }
        out[(size_t)bt * CH + tid] = (oa.x + oa.y) + (oa.z + oa.w);
    }
}

extern "C" void kernel_launch(void* const* d_in, const int* in_sizes, int n_in,
                              void* d_out, int out_size, void* d_ws, size_t ws_size,
                              hipStream_t stream) {
    const float* q_x  = (const float*)d_in[0];
    const float* kv_x = (const float*)d_in[1];
    const float* Wk   = (const float*)d_in[2];
    const float* Wq   = (const float*)d_in[3];
    const float* Wv   = (const float*)d_in[4];
    const float* bias = (const float*)d_in[5];
    const float* Ws   = (const float*)d_in[6];
    const float* bs   = (const float*)d_in[7];
    float* out = (float*)d_out;

    attn_kernel<<<dim3(B * T), dim3(256), 0, stream>>>(
        q_x, kv_x, Wk, Wq, Wv, bias, Ws, bs, out);
}